// Round 2
// baseline (588.762 us; speedup 1.0000x reference)
//
#include <hip/hip_runtime.h>
#include <math.h>

#define B_   16
#define C_   256
#define T_   8192
#define BINS 16
#define NFFT 30

// ---------------- Kernel 1: Gram partials  G = X X^T (fp32, K-split 4) ----------------
#define TK   16
#define LSTR 132   // 128 rows + 4 pad

__global__ __launch_bounds__(256) void gram_kernel(const float* __restrict__ x,
                                                   float* __restrict__ gp) {
  const int tp = blockIdx.x;   // 0,1,2 -> tiles (0,0),(0,1),(1,1)
  const int b  = blockIdx.y;
  const int ks = blockIdx.z;   // K split 0..3
  const int ti = (tp == 2) ? 1 : 0;
  const int tj = (tp == 0) ? 0 : 1;
  const bool diag = (ti == tj);

  __shared__ float As[TK * LSTR];
  __shared__ float Bs[TK * LSTR];

  const int tid = threadIdx.x;
  const int m = tid & 15;
  const int n = tid >> 4;

  float acc[8][8];
#pragma unroll
  for (int i = 0; i < 8; ++i)
#pragma unroll
    for (int j = 0; j < 8; ++j) acc[i][j] = 0.f;

  const float* xa = x + ((size_t)(b * C_ + ti * 128)) * T_;
  const float* xb = x + ((size_t)(b * C_ + tj * 128)) * T_;
  const int t0 = ks * 2048;

  for (int kt = 0; kt < 2048; kt += TK) {
#pragma unroll
    for (int h = 0; h < 2; ++h) {
      const int l = tid + h * 256;
      const int row = l >> 2, seg = l & 3;
      const float4 v = *(const float4*)(xa + (size_t)row * T_ + t0 + kt + seg * 4);
      As[(seg*4+0)*LSTR + row] = v.x;
      As[(seg*4+1)*LSTR + row] = v.y;
      As[(seg*4+2)*LSTR + row] = v.z;
      As[(seg*4+3)*LSTR + row] = v.w;
      if (!diag) {
        const float4 u = *(const float4*)(xb + (size_t)row * T_ + t0 + kt + seg * 4);
        Bs[(seg*4+0)*LSTR + row] = u.x;
        Bs[(seg*4+1)*LSTR + row] = u.y;
        Bs[(seg*4+2)*LSTR + row] = u.z;
        Bs[(seg*4+3)*LSTR + row] = u.w;
      }
    }
    __syncthreads();
    const float* Bp = diag ? As : Bs;
#pragma unroll
    for (int k = 0; k < TK; ++k) {
      const float4 a0 = *(const float4*)&As[k*LSTR + m*8];
      const float4 a1 = *(const float4*)&As[k*LSTR + m*8 + 4];
      const float4 b0 = *(const float4*)&Bp[k*LSTR + n*8];
      const float4 b1 = *(const float4*)&Bp[k*LSTR + n*8 + 4];
      const float av[8] = {a0.x,a0.y,a0.z,a0.w,a1.x,a1.y,a1.z,a1.w};
      const float bv[8] = {b0.x,b0.y,b0.z,b0.w,b1.x,b1.y,b1.z,b1.w};
#pragma unroll
      for (int i = 0; i < 8; ++i)
#pragma unroll
        for (int j = 0; j < 8; ++j)
          acc[i][j] += av[i] * bv[j];
    }
    __syncthreads();
  }

  float* g = gp + ((size_t)(ks * 16 + b)) * 65536;
#pragma unroll
  for (int i = 0; i < 8; ++i) {
    const int gi = ti*128 + m*8 + i;
    const float4 w0 = make_float4(acc[i][0], acc[i][1], acc[i][2], acc[i][3]);
    const float4 w1 = make_float4(acc[i][4], acc[i][5], acc[i][6], acc[i][7]);
    *(float4*)&g[(size_t)gi*256 + tj*128 + n*8]     = w0;
    *(float4*)&g[(size_t)gi*256 + tj*128 + n*8 + 4] = w1;
  }
  if (!diag) {
#pragma unroll
    for (int j = 0; j < 8; ++j)
#pragma unroll
      for (int i = 0; i < 8; ++i)
        g[(size_t)(tj*128 + n*8 + j)*256 + ti*128 + m*8 + i] = acc[i][j];
  }
}

// ---------------- Kernel 2: scores -> softmax -> M = P @ Wv (per batch) ----------------
__global__ __launch_bounds__(256) void attn_kernel(const float* __restrict__ Wk,
                                                   const float* __restrict__ Wq,
                                                   const float* __restrict__ Wv,
                                                   const float* __restrict__ gp,
                                                   float* __restrict__ Mout) {
  const int b = blockIdx.x;
  const int tid = threadIdx.x;
  __shared__ float s1[16*256];
  __shared__ float s2[16*256];
  __shared__ float invs[16];

  // Phase 1: WkG[cc][tid] = sum_C1 Wk[cc][C1] * G[C1][tid], G = sum of 4 partials
  float acc[16];
#pragma unroll
  for (int cc = 0; cc < 16; ++cc) acc[cc] = 0.f;
  const float* g0 = gp + (size_t)b * 65536;
  for (int c4 = 0; c4 < 64; ++c4) {
    float gv[4];
#pragma unroll
    for (int j = 0; j < 4; ++j) {
      const size_t off = (size_t)(c4*4 + j) * 256 + tid;
      gv[j] = g0[off] + g0[off + 1048576] + g0[off + 2097152] + g0[off + 3145728];
    }
#pragma unroll
    for (int cc = 0; cc < 16; ++cc) {
      const float4 w4 = *(const float4*)&Wk[cc*256 + c4*4];   // wave-uniform -> s_load
      acc[cc] += w4.x*gv[0] + w4.y*gv[1] + w4.z*gv[2] + w4.w*gv[3];
    }
  }
#pragma unroll
  for (int cc = 0; cc < 16; ++cc) s1[cc*256 + tid] = acc[cc];
  __syncthreads();

  // Phase 2: scores[cc][tid] = (1/16) sum_C2 WkG[cc][C2] * Wq[tid][C2]
  float sc[16];
#pragma unroll
  for (int cc = 0; cc < 16; ++cc) sc[cc] = 0.f;
  for (int c4 = 0; c4 < 64; ++c4) {
    const float4 wq4 = *(const float4*)&Wq[(size_t)tid*256 + c4*4];
#pragma unroll
    for (int cc = 0; cc < 16; ++cc) {
      const float4 p4 = *(const float4*)&s1[cc*256 + c4*4];
      sc[cc] += p4.x*wq4.x + p4.y*wq4.y + p4.z*wq4.z + p4.w*wq4.w;
    }
  }
#pragma unroll
  for (int cc = 0; cc < 16; ++cc) s2[cc*256 + tid] = sc[cc] * 0.0625f;
  __syncthreads();

  // softmax over rows of s2 (16 rows x 256)
  if (tid < 16) {
    float mx = -1e30f;
    for (int j = 0; j < 256; ++j) mx = fmaxf(mx, s2[tid*256 + j]);
    float sum = 0.f;
    for (int j = 0; j < 256; ++j) {
      const float e = expf(s2[tid*256 + j] - mx);
      s2[tid*256 + j] = e;
      sum += e;
    }
    invs[tid] = 1.f / sum;
  }
  __syncthreads();

  // Phase 4: M[cc][tid] = sum_CC P[cc][CC] * Wv[CC][tid]
  float mac[16];
#pragma unroll
  for (int cc = 0; cc < 16; ++cc) mac[cc] = 0.f;
  for (int c4 = 0; c4 < 64; ++c4) {
    float wv[4];
#pragma unroll
    for (int j = 0; j < 4; ++j) wv[j] = Wv[(size_t)(c4*4 + j)*256 + tid];
#pragma unroll
    for (int cc = 0; cc < 16; ++cc) {
      const float4 p4 = *(const float4*)&s2[cc*256 + c4*4];
      mac[cc] += p4.x*wv[0] + p4.y*wv[1] + p4.z*wv[2] + p4.w*wv[3];
    }
  }
#pragma unroll
  for (int cc = 0; cc < 16; ++cc)
    Mout[(size_t)b*4096 + cc*256 + tid] = mac[cc] * invs[cc];
}

// ---------------- Kernel 3: seq[b*16+cc][t] = sum_C M[b][cc][C] * x[b][C][t] ----------------
__global__ __launch_bounds__(256) void outp_kernel(const float* __restrict__ x,
                                                   const float* __restrict__ M,
                                                   float* __restrict__ seq) {
  const int tc = blockIdx.x;   // 0..7
  const int b  = blockIdx.y;
  const int tid = threadIdx.x;
  const int t  = tc*1024 + tid*4;
  const float* xb = x + (size_t)b*C_*T_ + t;
  const float* mb = M + (size_t)b*4096;
  float4 a[16];
#pragma unroll
  for (int cc = 0; cc < 16; ++cc) a[cc] = make_float4(0.f,0.f,0.f,0.f);
  for (int ch = 0; ch < 64; ++ch) {
    float4 xv[4];
#pragma unroll
    for (int j = 0; j < 4; ++j)
      xv[j] = *(const float4*)(xb + (size_t)(ch*4 + j) * T_);
#pragma unroll
    for (int cc = 0; cc < 16; ++cc) {
      const float4 m4 = *(const float4*)(mb + cc*256 + ch*4);   // wave-uniform
      a[cc].x += m4.x*xv[0].x + m4.y*xv[1].x + m4.z*xv[2].x + m4.w*xv[3].x;
      a[cc].y += m4.x*xv[0].y + m4.y*xv[1].y + m4.z*xv[2].y + m4.w*xv[3].y;
      a[cc].z += m4.x*xv[0].z + m4.y*xv[1].z + m4.z*xv[2].z + m4.w*xv[3].z;
      a[cc].w += m4.x*xv[0].w + m4.y*xv[1].w + m4.z*xv[2].w + m4.w*xv[3].w;
    }
  }
#pragma unroll
  for (int cc = 0; cc < 16; ++cc)
    *(float4*)(seq + (size_t)(b*16 + cc)*T_ + t) = a[cc];
}

// ---------------- Kernel 4: windowed-DFT power spectrogram ----------------
__global__ __launch_bounds__(256) void spec_kernel(const float* __restrict__ seq,
                                                   float* __restrict__ out) {
  const int tcx = blockIdx.x;  // 0..31 (256-t chunks)
  const int r   = blockIdx.y;  // 0..255 rows
  const int tid = threadIdx.x;
  const int t0  = tcx * 256;

  __shared__ float smem[288];
  __shared__ float ctab[BINS*NFFT];
  __shared__ float stab[BINS*NFFT];

  const float* row = seq + (size_t)r * T_;
  for (int i = tid; i < 288; i += 256) {
    int g = t0 - 15 + i;
    if (g < 0) g = -g;
    if (g > T_-1) g = 2*(T_-1) - g;
    smem[i] = row[g];
  }
  // FIX (R1 post-mortem): BINS*NFFT = 480 > 256 threads; the old `if (tid < 480)`
  // left ctab[256..479]/stab[256..479] = uninitialized LDS -> 3.5e7 absmax.
  for (int i = tid; i < BINS*NFFT; i += 256) {
    const int k = i / NFFT, n = i % NFFT;
    const float TWO_PI = 6.283185307179586f;
    const float wn = 0.5f - 0.5f * cosf(TWO_PI * (float)n / (float)NFFT);
    const float ang = TWO_PI * (float)(k * n) / (float)NFFT;
    ctab[i] = cosf(ang) * wn;
    stab[i] = sinf(ang) * wn;
  }
  __syncthreads();

  const int k   = tid >> 4;
  const int sub = tid & 15;
  float cr[NFFT], ci[NFFT];
#pragma unroll
  for (int n = 0; n < NFFT; ++n) { cr[n] = ctab[k*NFFT + n]; ci[n] = stab[k*NFFT + n]; }

  float* orow = out + (size_t)(r*BINS + k) * T_ + t0;
  const float inv_norm = 1.0f / 11.25f;   // 1 / sum(window^2)

  for (int jj = 0; jj < 4; ++jj) {
    const int x0 = 4*sub + 64*jj;
    float smp[36];
#pragma unroll
    for (int q = 0; q < 9; ++q) {
      const float4 v = *(const float4*)&smem[x0 + 4*q];
      smp[4*q+0] = v.x; smp[4*q+1] = v.y; smp[4*q+2] = v.z; smp[4*q+3] = v.w;
    }
    float4 pw;
#pragma unroll
    for (int p = 0; p < 4; ++p) {
      float re = 0.f, im = 0.f;
#pragma unroll
      for (int n = 0; n < NFFT; ++n) {
        re += cr[n] * smp[p + n];
        im += ci[n] * smp[p + n];
      }
      ((float*)&pw)[p] = (re*re + im*im) * inv_norm;
    }
    *(float4*)(orow + x0) = pw;
  }
}

// ---------------- launch ----------------
extern "C" void kernel_launch(void* const* d_in, const int* in_sizes, int n_in,
                              void* d_out, int out_size, void* d_ws, size_t ws_size,
                              hipStream_t stream) {
  const float* x  = (const float*)d_in[0];
  const float* Wk = (const float*)d_in[1];
  const float* Wq = (const float*)d_in[2];
  const float* Wv = (const float*)d_in[3];
  float* out = (float*)d_out;
  float* ws  = (float*)d_ws;

  float* gp  = ws;                 // 4 * 16 * 65536 floats = 16.78 MB
  float* M   = ws + 4194304;       // 16 * 16 * 256 floats
  float* seq = ws + 4259840;       // 256 * 8192 floats = 8.39 MB

  gram_kernel<<<dim3(3, 16, 4), 256, 0, stream>>>(x, gp);
  attn_kernel<<<dim3(16), 256, 0, stream>>>(Wk, Wq, Wv, gp, M);
  outp_kernel<<<dim3(8, 16), 256, 0, stream>>>(x, M, seq);
  spec_kernel<<<dim3(32, 256), 256, 0, stream>>>(seq, out);
}

// Round 3
// 332.529 us; speedup vs baseline: 1.7706x; 1.7706x over previous
//
#include <hip/hip_runtime.h>
#include <math.h>

#define B_   16
#define C_   256
#define T_   8192
#define BINS 16
#define NFFT 30

typedef __attribute__((ext_vector_type(8))) short bf16x8;
typedef __attribute__((ext_vector_type(4))) float f32x4;

static __device__ __forceinline__ unsigned short f2bf(float f) {
  unsigned u = __float_as_uint(f);
  u += 0x7fff + ((u >> 16) & 1);           // RNE to bf16
  return (unsigned short)(u >> 16);
}
static __device__ __forceinline__ float bf2f(unsigned short h) {
  return __uint_as_float(((unsigned)h) << 16);
}

// ---------------- Kernel 1: Gram partials via split-bf16 MFMA ----------------
// G = X X^T, X split x = h + l (bf16 each); G ~= h h^T + h l^T + l h^T.
// Grid (3 tiles, 16 b, 4 ks); 128x128 tile, BK=32, 4 waves of 64x64.
#define GLSTR 40   // 32 k-elems + 8 pad (ushort units)

__global__ __launch_bounds__(256) void gram_mfma(const float* __restrict__ x,
                                                 float* __restrict__ gp) {
  const int tp = blockIdx.x;   // 0:(0,0) 1:(0,1) 2:(1,1)
  const int b  = blockIdx.y;
  const int ks = blockIdx.z;
  const int ti = (tp == 2) ? 1 : 0;
  const int tj = (tp == 0) ? 0 : 1;
  const bool diag = (ti == tj);

  __shared__ unsigned short Ah[128*GLSTR], Al[128*GLSTR];
  __shared__ unsigned short Bh[128*GLSTR], Bl[128*GLSTR];

  const int tid  = threadIdx.x;
  const int lane = tid & 63;
  const int w    = tid >> 6;
  const int wr   = w >> 1, wc = w & 1;
  const int fr   = lane & 15;    // row within 16-tile (A: m, B: n)
  const int g    = lane >> 4;    // k-seg group 0..3 (k = g*8 + j)

  const int srow  = tid & 127;   // staging row
  const int khalf = tid >> 7;    // staging k-half
  const int sswz  = (srow >> 3) & 3;

  const float* xa = x + ((size_t)(b * C_ + ti * 128)) * T_;
  const float* xb = x + ((size_t)(b * C_ + tj * 128)) * T_;
  const int t0 = ks * 2048;

  f32x4 acc[4][4];
#pragma unroll
  for (int mt = 0; mt < 4; ++mt)
#pragma unroll
    for (int nt = 0; nt < 4; ++nt) acc[mt][nt] = (f32x4){0.f, 0.f, 0.f, 0.f};

  // fragment read offsets (swizzle-aware), in ushort elems
  int aoff[4], boff[4];
#pragma unroll
  for (int mt = 0; mt < 4; ++mt) {
    const int row = wr*64 + mt*16 + fr;
    aoff[mt] = row*GLSTR + ((g ^ ((row >> 3) & 3)) << 3);
  }
#pragma unroll
  for (int nt = 0; nt < 4; ++nt) {
    const int row = wc*64 + nt*16 + fr;
    boff[nt] = row*GLSTR + ((g ^ ((row >> 3) & 3)) << 3);
  }

  for (int kt = 0; kt < 2048; kt += 32) {
#pragma unroll
    for (int q = 0; q < 4; ++q) {
      const int k4  = khalf*4 + q;           // 0..7
      const int k4s = k4 ^ (sswz << 1);      // even-xor: keeps b128 pairs contiguous
      const int dst = srow*GLSTR + k4s*4;
      {
        const float4 v = *(const float4*)(xa + (size_t)srow*T_ + t0 + kt + k4*4);
        unsigned short h0=f2bf(v.x), h1=f2bf(v.y), h2=f2bf(v.z), h3=f2bf(v.w);
        ushort4 hh; hh.x=h0; hh.y=h1; hh.z=h2; hh.w=h3;
        ushort4 ll; ll.x=f2bf(v.x-bf2f(h0)); ll.y=f2bf(v.y-bf2f(h1));
        ll.z=f2bf(v.z-bf2f(h2)); ll.w=f2bf(v.w-bf2f(h3));
        *(ushort4*)&Ah[dst] = hh;
        *(ushort4*)&Al[dst] = ll;
      }
      if (!diag) {
        const float4 v = *(const float4*)(xb + (size_t)srow*T_ + t0 + kt + k4*4);
        unsigned short h0=f2bf(v.x), h1=f2bf(v.y), h2=f2bf(v.z), h3=f2bf(v.w);
        ushort4 hh; hh.x=h0; hh.y=h1; hh.z=h2; hh.w=h3;
        ushort4 ll; ll.x=f2bf(v.x-bf2f(h0)); ll.y=f2bf(v.y-bf2f(h1));
        ll.z=f2bf(v.z-bf2f(h2)); ll.w=f2bf(v.w-bf2f(h3));
        *(ushort4*)&Bh[dst] = hh;
        *(ushort4*)&Bl[dst] = ll;
      }
    }
    __syncthreads();

    const unsigned short* BH = diag ? Ah : Bh;
    const unsigned short* BL = diag ? Al : Bl;

    bf16x8 fah[4], fal[4], fbh[4], fbl[4];
#pragma unroll
    for (int mt = 0; mt < 4; ++mt) {
      fah[mt] = *(const bf16x8*)&Ah[aoff[mt]];
      fal[mt] = *(const bf16x8*)&Al[aoff[mt]];
    }
#pragma unroll
    for (int nt = 0; nt < 4; ++nt) {
      fbh[nt] = *(const bf16x8*)&BH[boff[nt]];
      fbl[nt] = *(const bf16x8*)&BL[boff[nt]];
    }
#pragma unroll
    for (int mt = 0; mt < 4; ++mt)
#pragma unroll
      for (int nt = 0; nt < 4; ++nt) {
        acc[mt][nt] = __builtin_amdgcn_mfma_f32_16x16x32_bf16(fah[mt], fbh[nt], acc[mt][nt], 0, 0, 0);
        acc[mt][nt] = __builtin_amdgcn_mfma_f32_16x16x32_bf16(fah[mt], fbl[nt], acc[mt][nt], 0, 0, 0);
        acc[mt][nt] = __builtin_amdgcn_mfma_f32_16x16x32_bf16(fal[mt], fbh[nt], acc[mt][nt], 0, 0, 0);
      }
    __syncthreads();
  }

  float* gpart = gp + ((size_t)(ks * 16 + b)) * 65536;
#pragma unroll
  for (int mt = 0; mt < 4; ++mt)
#pragma unroll
    for (int nt = 0; nt < 4; ++nt)
#pragma unroll
      for (int r = 0; r < 4; ++r) {
        const int gi = ti*128 + wr*64 + mt*16 + g*4 + r;
        const int gj = tj*128 + wc*64 + nt*16 + fr;
        gpart[(size_t)gi*256 + gj] = acc[mt][nt][r];
        if (!diag) gpart[(size_t)gj*256 + gi] = acc[mt][nt][r];
      }
}

// ---------------- Kernel 2a: reduce partials + WkG (parallel, 128 blocks) ----------------
__global__ __launch_bounds__(256) void attn_a(const float* __restrict__ Wk,
                                              const float* __restrict__ gp,
                                              float* __restrict__ wkg) {
  const int tc = blockIdx.x;   // 0..7 (32-col chunks)
  const int b  = blockIdx.y;
  const int tid = threadIdx.x;
  __shared__ float gl[256*32];

  const float* g0 = gp + (size_t)b*65536 + tc*32;
#pragma unroll
  for (int i = 0; i < 32; ++i) {
    const int idx = i*256 + tid;
    const int r = idx >> 5, cl = idx & 31;
    const size_t off = (size_t)r*256 + cl;
    gl[r*32 + cl] = g0[off] + g0[off + 1048576] + g0[off + 2097152] + g0[off + 3145728];
  }
  __syncthreads();

  const int cl  = tid & 31;
  const int cc0 = (tid >> 5) * 2;
#pragma unroll
  for (int h = 0; h < 2; ++h) {
    const int cc = cc0 + h;
    float a = 0.f;
    for (int c1 = 0; c1 < 256; c1 += 4) {
      const float4 w4 = *(const float4*)&Wk[cc*256 + c1];
      a += w4.x*gl[(c1+0)*32+cl] + w4.y*gl[(c1+1)*32+cl]
         + w4.z*gl[(c1+2)*32+cl] + w4.w*gl[(c1+3)*32+cl];
    }
    wkg[((size_t)b*16 + cc)*256 + tc*32 + cl] = a;
  }
}

// ---------------- Kernel 2b: scores -> softmax -> M = P @ Wv ----------------
__global__ __launch_bounds__(256) void attn_b(const float* __restrict__ Wq,
                                              const float* __restrict__ Wv,
                                              const float* __restrict__ wkg,
                                              float* __restrict__ Mout) {
  const int b = blockIdx.x;
  const int tid = threadIdx.x;
  __shared__ float s1[16*256];
  __shared__ float s2[16*256];
  __shared__ float invs[16];

#pragma unroll
  for (int cc = 0; cc < 16; ++cc) s1[cc*256 + tid] = wkg[((size_t)b*16 + cc)*256 + tid];
  __syncthreads();

  float sc[16];
#pragma unroll
  for (int cc = 0; cc < 16; ++cc) sc[cc] = 0.f;
  for (int c4 = 0; c4 < 64; ++c4) {
    const float4 wq4 = *(const float4*)&Wq[(size_t)tid*256 + c4*4];
#pragma unroll
    for (int cc = 0; cc < 16; ++cc) {
      const float4 p4 = *(const float4*)&s1[cc*256 + c4*4];
      sc[cc] += p4.x*wq4.x + p4.y*wq4.y + p4.z*wq4.z + p4.w*wq4.w;
    }
  }
#pragma unroll
  for (int cc = 0; cc < 16; ++cc) s2[cc*256 + tid] = sc[cc] * 0.0625f;
  __syncthreads();

  // parallel softmax: 16 rows x 16 lanes
  {
    const int rr = tid >> 4, jj = tid & 15;
    float mx = -1e30f;
    for (int c = jj; c < 256; c += 16) mx = fmaxf(mx, s2[rr*256 + c]);
    for (int o = 1; o < 16; o <<= 1) mx = fmaxf(mx, __shfl_xor(mx, o, 64));
    float sm = 0.f;
    for (int c = jj; c < 256; c += 16) {
      const float e = __expf(s2[rr*256 + c] - mx);
      s2[rr*256 + c] = e;
      sm += e;
    }
    for (int o = 1; o < 16; o <<= 1) sm += __shfl_xor(sm, o, 64);
    if (jj == 0) invs[rr] = 1.f / sm;
  }
  __syncthreads();

  float mac[16];
#pragma unroll
  for (int cc = 0; cc < 16; ++cc) mac[cc] = 0.f;
  for (int c4 = 0; c4 < 64; ++c4) {
    float wv[4];
#pragma unroll
    for (int j = 0; j < 4; ++j) wv[j] = Wv[(size_t)(c4*4 + j)*256 + tid];
#pragma unroll
    for (int cc = 0; cc < 16; ++cc) {
      const float4 p4 = *(const float4*)&s2[cc*256 + c4*4];
      mac[cc] += p4.x*wv[0] + p4.y*wv[1] + p4.z*wv[2] + p4.w*wv[3];
    }
  }
#pragma unroll
  for (int cc = 0; cc < 16; ++cc)
    Mout[(size_t)b*4096 + cc*256 + tid] = mac[cc] * invs[cc];
}

// ---------------- Kernel 3: seq = M @ X  (256 blocks, float2) ----------------
__global__ __launch_bounds__(256) void outp_kernel(const float* __restrict__ x,
                                                   const float* __restrict__ M,
                                                   float* __restrict__ seq) {
  const int tc = blockIdx.x;   // 0..15
  const int b  = blockIdx.y;
  const int tid = threadIdx.x;
  const int t  = tc*512 + tid*2;
  const float* xb = x + (size_t)b*C_*T_ + t;
  const float* mb = M + (size_t)b*4096;
  float2 a[16];
#pragma unroll
  for (int cc = 0; cc < 16; ++cc) a[cc] = make_float2(0.f, 0.f);
  for (int ch = 0; ch < 64; ++ch) {
    float2 xv[4];
#pragma unroll
    for (int j = 0; j < 4; ++j)
      xv[j] = *(const float2*)(xb + (size_t)(ch*4 + j) * T_);
#pragma unroll
    for (int cc = 0; cc < 16; ++cc) {
      const float4 m4 = *(const float4*)(mb + cc*256 + ch*4);   // wave-uniform
      a[cc].x += m4.x*xv[0].x + m4.y*xv[1].x + m4.z*xv[2].x + m4.w*xv[3].x;
      a[cc].y += m4.x*xv[0].y + m4.y*xv[1].y + m4.z*xv[2].y + m4.w*xv[3].y;
    }
  }
#pragma unroll
  for (int cc = 0; cc < 16; ++cc)
    *(float2*)(seq + (size_t)(b*16 + cc)*T_ + t) = a[cc];
}

// ---------------- Kernel 4: windowed-DFT power spectrogram ----------------
__global__ __launch_bounds__(256) void spec_kernel(const float* __restrict__ seq,
                                                   float* __restrict__ out) {
  const int tcx = blockIdx.x;  // 0..31
  const int r   = blockIdx.y;  // 0..255
  const int tid = threadIdx.x;
  const int t0  = tcx * 256;

  __shared__ float smem[288];
  __shared__ float ctab[BINS*NFFT];
  __shared__ float stab[BINS*NFFT];

  const float* row = seq + (size_t)r * T_;
  for (int i = tid; i < 288; i += 256) {
    int gg = t0 - 15 + i;
    if (gg < 0) gg = -gg;
    if (gg > T_-1) gg = 2*(T_-1) - gg;
    smem[i] = row[gg];
  }
  for (int i = tid; i < BINS*NFFT; i += 256) {
    const int k = i / NFFT, n = i % NFFT;
    const float TWO_PI = 6.283185307179586f;
    const float wn = 0.5f - 0.5f * cosf(TWO_PI * (float)n / (float)NFFT);
    const float ang = TWO_PI * (float)(k * n) / (float)NFFT;
    ctab[i] = cosf(ang) * wn;
    stab[i] = sinf(ang) * wn;
  }
  __syncthreads();

  const int k   = tid >> 4;
  const int sub = tid & 15;
  float cr[NFFT], ci[NFFT];
#pragma unroll
  for (int n = 0; n < NFFT; ++n) { cr[n] = ctab[k*NFFT + n]; ci[n] = stab[k*NFFT + n]; }

  float* orow = out + (size_t)(r*BINS + k) * T_ + t0;
  const float inv_norm = 1.0f / 11.25f;

  for (int jj = 0; jj < 4; ++jj) {
    const int x0 = 4*sub + 64*jj;
    float smp[36];
#pragma unroll
    for (int q = 0; q < 9; ++q) {
      const float4 v = *(const float4*)&smem[x0 + 4*q];
      smp[4*q+0] = v.x; smp[4*q+1] = v.y; smp[4*q+2] = v.z; smp[4*q+3] = v.w;
    }
    float4 pw;
#pragma unroll
    for (int p = 0; p < 4; ++p) {
      float re = 0.f, im = 0.f;
#pragma unroll
      for (int n = 0; n < NFFT; ++n) {
        re += cr[n] * smp[p + n];
        im += ci[n] * smp[p + n];
      }
      ((float*)&pw)[p] = (re*re + im*im) * inv_norm;
    }
    *(float4*)(orow + x0) = pw;
  }
}

// ---------------- launch ----------------
extern "C" void kernel_launch(void* const* d_in, const int* in_sizes, int n_in,
                              void* d_out, int out_size, void* d_ws, size_t ws_size,
                              hipStream_t stream) {
  const float* x  = (const float*)d_in[0];
  const float* Wk = (const float*)d_in[1];
  const float* Wq = (const float*)d_in[2];
  const float* Wv = (const float*)d_in[3];
  float* out = (float*)d_out;
  float* ws  = (float*)d_ws;

  float* gp  = ws;                 // 4*16*65536      = 16.78 MB
  float* wkg = ws + 4194304;       // 16*16*256       = 0.26 MB
  float* M   = ws + 4259840;       // 16*16*256       = 0.26 MB
  float* seq = ws + 4325376;       // 256*8192        = 8.39 MB

  gram_mfma<<<dim3(3, 16, 4), 256, 0, stream>>>(x, gp);
  attn_a<<<dim3(8, 16), 256, 0, stream>>>(Wk, gp, wkg);
  attn_b<<<dim3(16), 256, 0, stream>>>(Wq, Wv, wkg, M);
  outp_kernel<<<dim3(16, 16), 256, 0, stream>>>(x, M, seq);
  spec_kernel<<<dim3(32, 256), 256, 0, stream>>>(seq, out);
}

// Round 4
// 269.061 us; speedup vs baseline: 2.1882x; 1.2359x over previous
//
#include <hip/hip_runtime.h>
#include <math.h>

#define B_   16
#define C_   256
#define T_   8192
#define BINS 16
#define NFFT 30
#define NP   8          // K-split count

typedef __attribute__((ext_vector_type(8))) short bf16x8;
typedef __attribute__((ext_vector_type(4))) float f32x4;

static __device__ __forceinline__ unsigned short f2bf(float f) {
  unsigned u = __float_as_uint(f);
  u += 0x7fff + ((u >> 16) & 1);           // RNE to bf16
  return (unsigned short)(u >> 16);
}
static __device__ __forceinline__ float bf2f(unsigned short h) {
  return __uint_as_float(((unsigned)h) << 16);
}

// ---------------- Kernel 1: Gram partials via split-bf16 MFMA ----------------
// G = X X^T, x = h + l (bf16 each); G ~= h h^T + h l^T + l h^T.
// Grid (3 tiles, 16 b, NP ks); 128x128 tile, BK=32, 8 waves of 64x32.
#define GLSTR 40   // 32 k-elems + 8 pad (ushort units)

__global__ __launch_bounds__(512) void gram_mfma(const float* __restrict__ x,
                                                 float* __restrict__ gp) {
  const int tp = blockIdx.x;   // 0:(0,0) 1:(0,1) 2:(1,1)
  const int b  = blockIdx.y;
  const int ks = blockIdx.z;
  const int ti = (tp == 2) ? 1 : 0;
  const int tj = (tp == 0) ? 0 : 1;
  const bool diag = (ti == tj);

  __shared__ unsigned short Ah[128*GLSTR], Al[128*GLSTR];
  __shared__ unsigned short Bh[128*GLSTR], Bl[128*GLSTR];

  const int tid  = threadIdx.x;
  const int lane = tid & 63;
  const int w    = tid >> 6;       // 0..7
  const int wr   = w >> 2;         // 0..1  (64-row block)
  const int wc   = w & 3;          // 0..3  (32-col block)
  const int fr   = lane & 15;      // row within 16-tile
  const int g    = lane >> 4;      // k-seg group 0..3

  const float* xa = x + ((size_t)(b * C_ + ti * 128)) * T_;
  const float* xb = x + ((size_t)(b * C_ + tj * 128)) * T_;
  const int t0 = ks * (T_ / NP);

  f32x4 acc[4][2];
#pragma unroll
  for (int mt = 0; mt < 4; ++mt)
#pragma unroll
    for (int nt = 0; nt < 2; ++nt) acc[mt][nt] = (f32x4){0.f, 0.f, 0.f, 0.f};

  // fragment read offsets (swizzle-aware), in ushort elems
  int aoff[4], boff[2];
#pragma unroll
  for (int mt = 0; mt < 4; ++mt) {
    const int row = wr*64 + mt*16 + fr;
    aoff[mt] = row*GLSTR + ((g ^ ((row >> 3) & 3)) << 3);
  }
#pragma unroll
  for (int nt = 0; nt < 2; ++nt) {
    const int row = wc*32 + nt*16 + fr;
    boff[nt] = row*GLSTR + ((g ^ ((row >> 3) & 3)) << 3);
  }

  for (int kt = 0; kt < T_ / NP; kt += 32) {
#pragma unroll
    for (int h = 0; h < 2; ++h) {
      const int idx = tid + h*512;          // 0..1023
      const int row = idx >> 3;             // 0..127
      const int seg = idx & 7;              // 0..7 (float4 segments of 32 k)
      const int k4s = seg ^ (((row >> 3) & 3) << 1);
      const int dst = row*GLSTR + k4s*4;
      {
        const float4 v = *(const float4*)(xa + (size_t)row*T_ + t0 + kt + seg*4);
        unsigned short h0=f2bf(v.x), h1=f2bf(v.y), h2=f2bf(v.z), h3=f2bf(v.w);
        ushort4 hh; hh.x=h0; hh.y=h1; hh.z=h2; hh.w=h3;
        ushort4 ll; ll.x=f2bf(v.x-bf2f(h0)); ll.y=f2bf(v.y-bf2f(h1));
        ll.z=f2bf(v.z-bf2f(h2)); ll.w=f2bf(v.w-bf2f(h3));
        *(ushort4*)&Ah[dst] = hh;
        *(ushort4*)&Al[dst] = ll;
      }
      if (!diag) {
        const float4 v = *(const float4*)(xb + (size_t)row*T_ + t0 + kt + seg*4);
        unsigned short h0=f2bf(v.x), h1=f2bf(v.y), h2=f2bf(v.z), h3=f2bf(v.w);
        ushort4 hh; hh.x=h0; hh.y=h1; hh.z=h2; hh.w=h3;
        ushort4 ll; ll.x=f2bf(v.x-bf2f(h0)); ll.y=f2bf(v.y-bf2f(h1));
        ll.z=f2bf(v.z-bf2f(h2)); ll.w=f2bf(v.w-bf2f(h3));
        *(ushort4*)&Bh[dst] = hh;
        *(ushort4*)&Bl[dst] = ll;
      }
    }
    __syncthreads();

    const unsigned short* BH = diag ? Ah : Bh;
    const unsigned short* BL = diag ? Al : Bl;

    bf16x8 fah[4], fal[4], fbh[2], fbl[2];
#pragma unroll
    for (int mt = 0; mt < 4; ++mt) {
      fah[mt] = *(const bf16x8*)&Ah[aoff[mt]];
      fal[mt] = *(const bf16x8*)&Al[aoff[mt]];
    }
#pragma unroll
    for (int nt = 0; nt < 2; ++nt) {
      fbh[nt] = *(const bf16x8*)&BH[boff[nt]];
      fbl[nt] = *(const bf16x8*)&BL[boff[nt]];
    }
#pragma unroll
    for (int mt = 0; mt < 4; ++mt)
#pragma unroll
      for (int nt = 0; nt < 2; ++nt) {
        acc[mt][nt] = __builtin_amdgcn_mfma_f32_16x16x32_bf16(fah[mt], fbh[nt], acc[mt][nt], 0, 0, 0);
        acc[mt][nt] = __builtin_amdgcn_mfma_f32_16x16x32_bf16(fah[mt], fbl[nt], acc[mt][nt], 0, 0, 0);
        acc[mt][nt] = __builtin_amdgcn_mfma_f32_16x16x32_bf16(fal[mt], fbh[nt], acc[mt][nt], 0, 0, 0);
      }
    __syncthreads();
  }

  float* gpart = gp + ((size_t)(ks * 16 + b)) * 65536;
#pragma unroll
  for (int mt = 0; mt < 4; ++mt)
#pragma unroll
    for (int nt = 0; nt < 2; ++nt)
#pragma unroll
      for (int r = 0; r < 4; ++r) {
        const int gi = ti*128 + wr*64 + mt*16 + g*4 + r;
        const int gj = tj*128 + wc*32 + nt*16 + fr;
        gpart[(size_t)gi*256 + gj] = acc[mt][nt][r];
        if (!diag) gpart[(size_t)gj*256 + gi] = acc[mt][nt][r];
      }
}

// ---------------- Kernel 2a: reduce NP partials + WkG (128 blocks) ----------------
__global__ __launch_bounds__(256) void attn_a(const float* __restrict__ Wk,
                                              const float* __restrict__ gp,
                                              float* __restrict__ wkg) {
  const int tc = blockIdx.x;   // 0..7 (32-col chunks)
  const int b  = blockIdx.y;
  const int tid = threadIdx.x;
  __shared__ float gl[256*32];

  const float* g0 = gp + (size_t)b*65536 + tc*32;
#pragma unroll
  for (int i = 0; i < 32; ++i) {
    const int idx = i*256 + tid;
    const int r = idx >> 5, cl = idx & 31;
    const size_t off = (size_t)r*256 + cl;
    float s = 0.f;
#pragma unroll
    for (int p = 0; p < NP; ++p) s += g0[off + (size_t)p*1048576];
    gl[r*32 + cl] = s;
  }
  __syncthreads();

  const int cl  = tid & 31;
  const int cc0 = (tid >> 5) * 2;
#pragma unroll
  for (int h = 0; h < 2; ++h) {
    const int cc = cc0 + h;
    float a = 0.f;
    for (int c1 = 0; c1 < 256; c1 += 4) {
      const float4 w4 = *(const float4*)&Wk[cc*256 + c1];
      a += w4.x*gl[(c1+0)*32+cl] + w4.y*gl[(c1+1)*32+cl]
         + w4.z*gl[(c1+2)*32+cl] + w4.w*gl[(c1+3)*32+cl];
    }
    wkg[((size_t)b*16 + cc)*256 + tc*32 + cl] = a;
  }
}

// ---------------- Kernel 2b: scores -> softmax -> M = P @ Wv ----------------
__global__ __launch_bounds__(256) void attn_b(const float* __restrict__ Wq,
                                              const float* __restrict__ Wv,
                                              const float* __restrict__ wkg,
                                              float* __restrict__ Mout) {
  const int b = blockIdx.x;
  const int tid = threadIdx.x;
  __shared__ float s1[16*256];
  __shared__ float s2[16*256];
  __shared__ float invs[16];

#pragma unroll
  for (int cc = 0; cc < 16; ++cc) s1[cc*256 + tid] = wkg[((size_t)b*16 + cc)*256 + tid];
  __syncthreads();

  float sc[16];
#pragma unroll
  for (int cc = 0; cc < 16; ++cc) sc[cc] = 0.f;
  for (int c4 = 0; c4 < 64; ++c4) {
    const float4 wq4 = *(const float4*)&Wq[(size_t)tid*256 + c4*4];
#pragma unroll
    for (int cc = 0; cc < 16; ++cc) {
      const float4 p4 = *(const float4*)&s1[cc*256 + c4*4];
      sc[cc] += p4.x*wq4.x + p4.y*wq4.y + p4.z*wq4.z + p4.w*wq4.w;
    }
  }
#pragma unroll
  for (int cc = 0; cc < 16; ++cc) s2[cc*256 + tid] = sc[cc] * 0.0625f;
  __syncthreads();

  // parallel softmax: 16 rows x 16 lanes
  {
    const int rr = tid >> 4, jj = tid & 15;
    float mx = -1e30f;
    for (int c = jj; c < 256; c += 16) mx = fmaxf(mx, s2[rr*256 + c]);
    for (int o = 1; o < 16; o <<= 1) mx = fmaxf(mx, __shfl_xor(mx, o, 64));
    float sm = 0.f;
    for (int c = jj; c < 256; c += 16) {
      const float e = __expf(s2[rr*256 + c] - mx);
      s2[rr*256 + c] = e;
      sm += e;
    }
    for (int o = 1; o < 16; o <<= 1) sm += __shfl_xor(sm, o, 64);
    if (jj == 0) invs[rr] = 1.f / sm;
  }
  __syncthreads();

  float mac[16];
#pragma unroll
  for (int cc = 0; cc < 16; ++cc) mac[cc] = 0.f;
  for (int c4 = 0; c4 < 64; ++c4) {
    float wv[4];
#pragma unroll
    for (int j = 0; j < 4; ++j) wv[j] = Wv[(size_t)(c4*4 + j)*256 + tid];
#pragma unroll
    for (int cc = 0; cc < 16; ++cc) {
      const float4 p4 = *(const float4*)&s2[cc*256 + c4*4];
      mac[cc] += p4.x*wv[0] + p4.y*wv[1] + p4.z*wv[2] + p4.w*wv[3];
    }
  }
#pragma unroll
  for (int cc = 0; cc < 16; ++cc)
    Mout[(size_t)b*4096 + cc*256 + tid] = mac[cc] * invs[cc];
}

// ---------------- Kernel 3: seq = M @ X  (256 blocks, float2) ----------------
__global__ __launch_bounds__(256) void outp_kernel(const float* __restrict__ x,
                                                   const float* __restrict__ M,
                                                   float* __restrict__ seq) {
  const int tc = blockIdx.x;   // 0..15
  const int b  = blockIdx.y;
  const int tid = threadIdx.x;
  const int t  = tc*512 + tid*2;
  const float* xb = x + (size_t)b*C_*T_ + t;
  const float* mb = M + (size_t)b*4096;
  float2 a[16];
#pragma unroll
  for (int cc = 0; cc < 16; ++cc) a[cc] = make_float2(0.f, 0.f);
  for (int ch = 0; ch < 64; ++ch) {
    float2 xv[4];
#pragma unroll
    for (int j = 0; j < 4; ++j)
      xv[j] = *(const float2*)(xb + (size_t)(ch*4 + j) * T_);
#pragma unroll
    for (int cc = 0; cc < 16; ++cc) {
      const float4 m4 = *(const float4*)(mb + cc*256 + ch*4);   // wave-uniform
      a[cc].x += m4.x*xv[0].x + m4.y*xv[1].x + m4.z*xv[2].x + m4.w*xv[3].x;
      a[cc].y += m4.x*xv[0].y + m4.y*xv[1].y + m4.z*xv[2].y + m4.w*xv[3].y;
    }
  }
#pragma unroll
  for (int cc = 0; cc < 16; ++cc)
    *(float2*)(seq + (size_t)(b*16 + cc)*T_ + t) = a[cc];
}

// ---------------- Kernel 4: windowed-DFT power spectrogram ----------------
__global__ __launch_bounds__(256) void spec_kernel(const float* __restrict__ seq,
                                                   float* __restrict__ out) {
  const int tcx = blockIdx.x;  // 0..31
  const int r   = blockIdx.y;  // 0..255
  const int tid = threadIdx.x;
  const int t0  = tcx * 256;

  __shared__ float smem[288];
  __shared__ float ctab[BINS*NFFT];
  __shared__ float stab[BINS*NFFT];

  const float* row = seq + (size_t)r * T_;
  for (int i = tid; i < 288; i += 256) {
    int gg = t0 - 15 + i;
    if (gg < 0) gg = -gg;
    if (gg > T_-1) gg = 2*(T_-1) - gg;
    smem[i] = row[gg];
  }
  for (int i = tid; i < BINS*NFFT; i += 256) {
    const int k = i / NFFT, n = i % NFFT;
    const float TWO_PI = 6.283185307179586f;
    const float wn = 0.5f - 0.5f * cosf(TWO_PI * (float)n / (float)NFFT);
    const float ang = TWO_PI * (float)(k * n) / (float)NFFT;
    ctab[i] = cosf(ang) * wn;
    stab[i] = sinf(ang) * wn;
  }
  __syncthreads();

  const int k   = tid >> 4;
  const int sub = tid & 15;
  float cr[NFFT], ci[NFFT];
#pragma unroll
  for (int n = 0; n < NFFT; ++n) { cr[n] = ctab[k*NFFT + n]; ci[n] = stab[k*NFFT + n]; }

  float* orow = out + (size_t)(r*BINS + k) * T_ + t0;
  const float inv_norm = 1.0f / 11.25f;

  for (int jj = 0; jj < 4; ++jj) {
    const int x0 = 4*sub + 64*jj;
    float smp[36];
#pragma unroll
    for (int q = 0; q < 9; ++q) {
      const float4 v = *(const float4*)&smem[x0 + 4*q];
      smp[4*q+0] = v.x; smp[4*q+1] = v.y; smp[4*q+2] = v.z; smp[4*q+3] = v.w;
    }
    float4 pw;
#pragma unroll
    for (int p = 0; p < 4; ++p) {
      float re = 0.f, im = 0.f;
#pragma unroll
      for (int n = 0; n < NFFT; ++n) {
        re += cr[n] * smp[p + n];
        im += ci[n] * smp[p + n];
      }
      ((float*)&pw)[p] = (re*re + im*im) * inv_norm;
    }
    *(float4*)(orow + x0) = pw;
  }
}

// ---------------- launch ----------------
extern "C" void kernel_launch(void* const* d_in, const int* in_sizes, int n_in,
                              void* d_out, int out_size, void* d_ws, size_t ws_size,
                              hipStream_t stream) {
  const float* x  = (const float*)d_in[0];
  const float* Wk = (const float*)d_in[1];
  const float* Wq = (const float*)d_in[2];
  const float* Wv = (const float*)d_in[3];
  float* out = (float*)d_out;
  float* ws  = (float*)d_ws;

  float* gp  = ws;                         // NP*16*65536 = 33.6 MB (NP=8)
  float* wkg = ws + (size_t)NP*1048576;    // 16*16*256
  float* M   = wkg + 65536;                // 16*16*256
  float* seq = M + 65536;                  // 256*8192 = 8.39 MB

  gram_mfma<<<dim3(3, 16, NP), 512, 0, stream>>>(x, gp);
  attn_a<<<dim3(8, 16), 256, 0, stream>>>(Wk, gp, wkg);
  attn_b<<<dim3(16), 256, 0, stream>>>(Wq, Wv, wkg, M);
  outp_kernel<<<dim3(16, 16), 256, 0, stream>>>(x, M, seq);
  spec_kernel<<<dim3(32, 256), 256, 0, stream>>>(seq, out);
}

// Round 5
// 264.188 us; speedup vs baseline: 2.2286x; 1.0184x over previous
//
#include <hip/hip_runtime.h>
#include <math.h>

#define B_   16
#define C_   256
#define T_   8192
#define BINS 16
#define NFFT 30
#define NP   8          // K-split count

typedef __attribute__((ext_vector_type(8))) short bf16x8;
typedef __attribute__((ext_vector_type(4))) float f32x4;

static __device__ __forceinline__ unsigned short f2bf(float f) {
  unsigned u = __float_as_uint(f);
  u += 0x7fff + ((u >> 16) & 1);           // RNE to bf16
  return (unsigned short)(u >> 16);
}
static __device__ __forceinline__ float bf2f(unsigned short h) {
  return __uint_as_float(((unsigned)h) << 16);
}

// ---------------- Kernel 1: Gram partials via split-bf16 MFMA ----------------
// G = X X^T, x = h + l (bf16 each); G ~= h h^T + h l^T + l h^T.
// R5: 4 quadrant tiles (no symmetric mirror) -> 512 blocks = 2/CU for TLP.
// Grid (4 tiles, 16 b, NP ks); 128x128 tile, BK=32, 8 waves of 64x32.
#define GLSTR 40   // 32 k-elems + 8 pad (ushort units)

__global__ __launch_bounds__(512) void gram_mfma(const float* __restrict__ x,
                                                 float* __restrict__ gp) {
  const int tp = blockIdx.x;   // quadrant: ti = tp>>1, tj = tp&1
  const int b  = blockIdx.y;
  const int ks = blockIdx.z;
  const int ti = tp >> 1;
  const int tj = tp & 1;
  const bool diag = (ti == tj);

  __shared__ unsigned short Ah[128*GLSTR], Al[128*GLSTR];
  __shared__ unsigned short Bh[128*GLSTR], Bl[128*GLSTR];

  const int tid  = threadIdx.x;
  const int lane = tid & 63;
  const int w    = tid >> 6;       // 0..7
  const int wr   = w >> 2;         // 0..1  (64-row block)
  const int wc   = w & 3;          // 0..3  (32-col block)
  const int fr   = lane & 15;      // row within 16-tile
  const int g    = lane >> 4;      // k-seg group 0..3

  const float* xa = x + ((size_t)(b * C_ + ti * 128)) * T_;
  const float* xb = x + ((size_t)(b * C_ + tj * 128)) * T_;
  const int t0 = ks * (T_ / NP);

  f32x4 acc[4][2];
#pragma unroll
  for (int mt = 0; mt < 4; ++mt)
#pragma unroll
    for (int nt = 0; nt < 2; ++nt) acc[mt][nt] = (f32x4){0.f, 0.f, 0.f, 0.f};

  // fragment read offsets (swizzle-aware), in ushort elems
  int aoff[4], boff[2];
#pragma unroll
  for (int mt = 0; mt < 4; ++mt) {
    const int row = wr*64 + mt*16 + fr;
    aoff[mt] = row*GLSTR + ((g ^ ((row >> 3) & 3)) << 3);
  }
#pragma unroll
  for (int nt = 0; nt < 2; ++nt) {
    const int row = wc*32 + nt*16 + fr;
    boff[nt] = row*GLSTR + ((g ^ ((row >> 3) & 3)) << 3);
  }

  for (int kt = 0; kt < T_ / NP; kt += 32) {
#pragma unroll
    for (int h = 0; h < 2; ++h) {
      const int idx = tid + h*512;          // 0..1023
      const int row = idx >> 3;             // 0..127
      const int seg = idx & 7;              // 0..7 (float4 segments of 32 k)
      const int k4s = seg ^ (((row >> 3) & 3) << 1);
      const int dst = row*GLSTR + k4s*4;
      {
        const float4 v = *(const float4*)(xa + (size_t)row*T_ + t0 + kt + seg*4);
        unsigned short h0=f2bf(v.x), h1=f2bf(v.y), h2=f2bf(v.z), h3=f2bf(v.w);
        ushort4 hh; hh.x=h0; hh.y=h1; hh.z=h2; hh.w=h3;
        ushort4 ll; ll.x=f2bf(v.x-bf2f(h0)); ll.y=f2bf(v.y-bf2f(h1));
        ll.z=f2bf(v.z-bf2f(h2)); ll.w=f2bf(v.w-bf2f(h3));
        *(ushort4*)&Ah[dst] = hh;
        *(ushort4*)&Al[dst] = ll;
      }
      if (!diag) {
        const float4 v = *(const float4*)(xb + (size_t)row*T_ + t0 + kt + seg*4);
        unsigned short h0=f2bf(v.x), h1=f2bf(v.y), h2=f2bf(v.z), h3=f2bf(v.w);
        ushort4 hh; hh.x=h0; hh.y=h1; hh.z=h2; hh.w=h3;
        ushort4 ll; ll.x=f2bf(v.x-bf2f(h0)); ll.y=f2bf(v.y-bf2f(h1));
        ll.z=f2bf(v.z-bf2f(h2)); ll.w=f2bf(v.w-bf2f(h3));
        *(ushort4*)&Bh[dst] = hh;
        *(ushort4*)&Bl[dst] = ll;
      }
    }
    __syncthreads();

    const unsigned short* BH = diag ? Ah : Bh;
    const unsigned short* BL = diag ? Al : Bl;

    bf16x8 fah[4], fal[4], fbh[2], fbl[2];
#pragma unroll
    for (int mt = 0; mt < 4; ++mt) {
      fah[mt] = *(const bf16x8*)&Ah[aoff[mt]];
      fal[mt] = *(const bf16x8*)&Al[aoff[mt]];
    }
#pragma unroll
    for (int nt = 0; nt < 2; ++nt) {
      fbh[nt] = *(const bf16x8*)&BH[boff[nt]];
      fbl[nt] = *(const bf16x8*)&BL[boff[nt]];
    }
#pragma unroll
    for (int mt = 0; mt < 4; ++mt)
#pragma unroll
      for (int nt = 0; nt < 2; ++nt) {
        acc[mt][nt] = __builtin_amdgcn_mfma_f32_16x16x32_bf16(fah[mt], fbh[nt], acc[mt][nt], 0, 0, 0);
        acc[mt][nt] = __builtin_amdgcn_mfma_f32_16x16x32_bf16(fah[mt], fbl[nt], acc[mt][nt], 0, 0, 0);
        acc[mt][nt] = __builtin_amdgcn_mfma_f32_16x16x32_bf16(fal[mt], fbh[nt], acc[mt][nt], 0, 0, 0);
      }
    __syncthreads();
  }

  float* gpart = gp + ((size_t)(ks * 16 + b)) * 65536;
#pragma unroll
  for (int mt = 0; mt < 4; ++mt)
#pragma unroll
    for (int nt = 0; nt < 2; ++nt)
#pragma unroll
      for (int r = 0; r < 4; ++r) {
        const int gi = ti*128 + wr*64 + mt*16 + g*4 + r;
        const int gj = tj*128 + wc*32 + nt*16 + fr;
        gpart[(size_t)gi*256 + gj] = acc[mt][nt][r];
      }
}

// ---------------- Kernel 2a: reduce NP partials + WkG (128 blocks) ----------------
__global__ __launch_bounds__(256) void attn_a(const float* __restrict__ Wk,
                                              const float* __restrict__ gp,
                                              float* __restrict__ wkg) {
  const int tc = blockIdx.x;   // 0..7 (32-col chunks)
  const int b  = blockIdx.y;
  const int tid = threadIdx.x;
  __shared__ float gl[256*32];

  const float* g0 = gp + (size_t)b*65536 + tc*32;
#pragma unroll
  for (int i = 0; i < 32; ++i) {
    const int idx = i*256 + tid;
    const int r = idx >> 5, cl = idx & 31;
    const size_t off = (size_t)r*256 + cl;
    float s = 0.f;
#pragma unroll
    for (int p = 0; p < NP; ++p) s += g0[off + (size_t)p*1048576];
    gl[r*32 + cl] = s;
  }
  __syncthreads();

  const int cl  = tid & 31;
  const int cc0 = (tid >> 5) * 2;
#pragma unroll
  for (int h = 0; h < 2; ++h) {
    const int cc = cc0 + h;
    float a = 0.f;
    for (int c1 = 0; c1 < 256; c1 += 4) {
      const float4 w4 = *(const float4*)&Wk[cc*256 + c1];
      a += w4.x*gl[(c1+0)*32+cl] + w4.y*gl[(c1+1)*32+cl]
         + w4.z*gl[(c1+2)*32+cl] + w4.w*gl[(c1+3)*32+cl];
    }
    wkg[((size_t)b*16 + cc)*256 + tc*32 + cl] = a;
  }
}

// ---------------- Kernel 2b: scores -> softmax -> M = P @ Wv ----------------
__global__ __launch_bounds__(256) void attn_b(const float* __restrict__ Wq,
                                              const float* __restrict__ Wv,
                                              const float* __restrict__ wkg,
                                              float* __restrict__ Mout) {
  const int b = blockIdx.x;
  const int tid = threadIdx.x;
  __shared__ float s1[16*256];
  __shared__ float s2[16*256];
  __shared__ float invs[16];

#pragma unroll
  for (int cc = 0; cc < 16; ++cc) s1[cc*256 + tid] = wkg[((size_t)b*16 + cc)*256 + tid];
  __syncthreads();

  float sc[16];
#pragma unroll
  for (int cc = 0; cc < 16; ++cc) sc[cc] = 0.f;
  for (int c4 = 0; c4 < 64; ++c4) {
    const float4 wq4 = *(const float4*)&Wq[(size_t)tid*256 + c4*4];
#pragma unroll
    for (int cc = 0; cc < 16; ++cc) {
      const float4 p4 = *(const float4*)&s1[cc*256 + c4*4];
      sc[cc] += p4.x*wq4.x + p4.y*wq4.y + p4.z*wq4.z + p4.w*wq4.w;
    }
  }
#pragma unroll
  for (int cc = 0; cc < 16; ++cc) s2[cc*256 + tid] = sc[cc] * 0.0625f;
  __syncthreads();

  // parallel softmax: 16 rows x 16 lanes
  {
    const int rr = tid >> 4, jj = tid & 15;
    float mx = -1e30f;
    for (int c = jj; c < 256; c += 16) mx = fmaxf(mx, s2[rr*256 + c]);
    for (int o = 1; o < 16; o <<= 1) mx = fmaxf(mx, __shfl_xor(mx, o, 64));
    float sm = 0.f;
    for (int c = jj; c < 256; c += 16) {
      const float e = __expf(s2[rr*256 + c] - mx);
      s2[rr*256 + c] = e;
      sm += e;
    }
    for (int o = 1; o < 16; o <<= 1) sm += __shfl_xor(sm, o, 64);
    if (jj == 0) invs[rr] = 1.f / sm;
  }
  __syncthreads();

  float mac[16];
#pragma unroll
  for (int cc = 0; cc < 16; ++cc) mac[cc] = 0.f;
  for (int c4 = 0; c4 < 64; ++c4) {
    float wv[4];
#pragma unroll
    for (int j = 0; j < 4; ++j) wv[j] = Wv[(size_t)(c4*4 + j)*256 + tid];
#pragma unroll
    for (int cc = 0; cc < 16; ++cc) {
      const float4 p4 = *(const float4*)&s2[cc*256 + c4*4];
      mac[cc] += p4.x*wv[0] + p4.y*wv[1] + p4.z*wv[2] + p4.w*wv[3];
    }
  }
#pragma unroll
  for (int cc = 0; cc < 16; ++cc)
    Mout[(size_t)b*4096 + cc*256 + tid] = mac[cc] * invs[cc];
}

// ---------------- Kernel 3: seq = M @ X  (256 blocks, float2) ----------------
__global__ __launch_bounds__(256) void outp_kernel(const float* __restrict__ x,
                                                   const float* __restrict__ M,
                                                   float* __restrict__ seq) {
  const int tc = blockIdx.x;   // 0..15
  const int b  = blockIdx.y;
  const int tid = threadIdx.x;
  const int t  = tc*512 + tid*2;
  const float* xb = x + (size_t)b*C_*T_ + t;
  const float* mb = M + (size_t)b*4096;
  float2 a[16];
#pragma unroll
  for (int cc = 0; cc < 16; ++cc) a[cc] = make_float2(0.f, 0.f);
  for (int ch = 0; ch < 64; ++ch) {
    float2 xv[4];
#pragma unroll
    for (int j = 0; j < 4; ++j)
      xv[j] = *(const float2*)(xb + (size_t)(ch*4 + j) * T_);
#pragma unroll
    for (int cc = 0; cc < 16; ++cc) {
      const float4 m4 = *(const float4*)(mb + cc*256 + ch*4);   // wave-uniform
      a[cc].x += m4.x*xv[0].x + m4.y*xv[1].x + m4.z*xv[2].x + m4.w*xv[3].x;
      a[cc].y += m4.x*xv[0].y + m4.y*xv[1].y + m4.z*xv[2].y + m4.w*xv[3].y;
    }
  }
#pragma unroll
  for (int cc = 0; cc < 16; ++cc)
    *(float2*)(seq + (size_t)(b*16 + cc)*T_ + t) = a[cc];
}

// ---------------- Kernel 4: windowed-DFT power spectrogram ----------------
__global__ __launch_bounds__(256) void spec_kernel(const float* __restrict__ seq,
                                                   float* __restrict__ out) {
  const int tcx = blockIdx.x;  // 0..31
  const int r   = blockIdx.y;  // 0..255
  const int tid = threadIdx.x;
  const int t0  = tcx * 256;

  __shared__ float smem[288];
  __shared__ float ctab[BINS*NFFT];
  __shared__ float stab[BINS*NFFT];

  const float* row = seq + (size_t)r * T_;
  for (int i = tid; i < 288; i += 256) {
    int gg = t0 - 15 + i;
    if (gg < 0) gg = -gg;
    if (gg > T_-1) gg = 2*(T_-1) - gg;
    smem[i] = row[gg];
  }
  for (int i = tid; i < BINS*NFFT; i += 256) {
    const int k = i / NFFT, n = i % NFFT;
    const float TWO_PI = 6.283185307179586f;
    const float wn = 0.5f - 0.5f * cosf(TWO_PI * (float)n / (float)NFFT);
    const float ang = TWO_PI * (float)(k * n) / (float)NFFT;
    ctab[i] = cosf(ang) * wn;
    stab[i] = sinf(ang) * wn;
  }
  __syncthreads();

  const int k   = tid >> 4;
  const int sub = tid & 15;
  float cr[NFFT], ci[NFFT];
#pragma unroll
  for (int n = 0; n < NFFT; ++n) { cr[n] = ctab[k*NFFT + n]; ci[n] = stab[k*NFFT + n]; }

  float* orow = out + (size_t)(r*BINS + k) * T_ + t0;
  const float inv_norm = 1.0f / 11.25f;

  for (int jj = 0; jj < 4; ++jj) {
    const int x0 = 4*sub + 64*jj;
    float smp[36];
#pragma unroll
    for (int q = 0; q < 9; ++q) {
      const float4 v = *(const float4*)&smem[x0 + 4*q];
      smp[4*q+0] = v.x; smp[4*q+1] = v.y; smp[4*q+2] = v.z; smp[4*q+3] = v.w;
    }
    float4 pw;
#pragma unroll
    for (int p = 0; p < 4; ++p) {
      float re = 0.f, im = 0.f;
#pragma unroll
      for (int n = 0; n < NFFT; ++n) {
        re += cr[n] * smp[p + n];
        im += ci[n] * smp[p + n];
      }
      ((float*)&pw)[p] = (re*re + im*im) * inv_norm;
    }
    *(float4*)(orow + x0) = pw;
  }
}

// ---------------- launch ----------------
extern "C" void kernel_launch(void* const* d_in, const int* in_sizes, int n_in,
                              void* d_out, int out_size, void* d_ws, size_t ws_size,
                              hipStream_t stream) {
  const float* x  = (const float*)d_in[0];
  const float* Wk = (const float*)d_in[1];
  const float* Wq = (const float*)d_in[2];
  const float* Wv = (const float*)d_in[3];
  float* out = (float*)d_out;
  float* ws  = (float*)d_ws;

  float* gp  = ws;                         // NP*16*65536 = 33.6 MB (NP=8)
  float* wkg = ws + (size_t)NP*1048576;    // 16*16*256
  float* M   = wkg + 65536;                // 16*16*256
  float* seq = M + 65536;                  // 256*8192 = 8.39 MB

  gram_mfma<<<dim3(4, 16, NP), 512, 0, stream>>>(x, gp);
  attn_a<<<dim3(8, 16), 256, 0, stream>>>(Wk, gp, wkg);
  attn_b<<<dim3(16), 256, 0, stream>>>(Wq, Wv, wkg, M);
  outp_kernel<<<dim3(16, 16), 256, 0, stream>>>(x, M, seq);
  spec_kernel<<<dim3(32, 256), 256, 0, stream>>>(seq, out);
}